// Round 1
// baseline (5354.084 us; speedup 1.0000x reference)
//
#include <hip/hip_runtime.h>

// UniADMemory: NB=196*64=12544 tokens, D=HW=256, M=2048 memory slots.
// Round 0: correct fp32 pipeline (projections -> stats -> fused dual softmax-attention).

__global__ __launch_bounds__(256) void gemm_awt(
    const float* __restrict__ A, const float* __restrict__ W,
    float* __restrict__ C)
{
    // C[r][c] = sum_d A[r][d] * W[c][d]   (A: [R x 256], W: [256 x 256])
    __shared__ float As[16][68];  // [k][r], pad 68 (272B rows, 16B aligned)
    __shared__ float Ws[16][68];  // [k][c]
    const int tid = threadIdx.x;
    const int r0 = blockIdx.x * 64;
    const int c0 = blockIdx.y * 64;
    const int lr = tid >> 2;          // 0..63
    const int lk = (tid & 3) * 4;     // 0,4,8,12
    const int ty = tid >> 4;          // 0..15
    const int tx = tid & 15;          // 0..15
    float acc[4][4] = {};
    for (int d0 = 0; d0 < 256; d0 += 16) {
        float4 av = *(const float4*)(A + (size_t)(r0 + lr) * 256 + d0 + lk);
        float4 wv = *(const float4*)(W + (size_t)(c0 + lr) * 256 + d0 + lk);
        As[lk+0][lr] = av.x; As[lk+1][lr] = av.y; As[lk+2][lr] = av.z; As[lk+3][lr] = av.w;
        Ws[lk+0][lr] = wv.x; Ws[lk+1][lr] = wv.y; Ws[lk+2][lr] = wv.z; Ws[lk+3][lr] = wv.w;
        __syncthreads();
        #pragma unroll
        for (int kk = 0; kk < 16; ++kk) {
            float4 a = *(const float4*)&As[kk][ty * 4];
            float4 b = *(const float4*)&Ws[kk][tx * 4];
            float aa[4] = {a.x, a.y, a.z, a.w};
            float bb[4] = {b.x, b.y, b.z, b.w};
            #pragma unroll
            for (int i = 0; i < 4; ++i)
                #pragma unroll
                for (int j = 0; j < 4; ++j)
                    acc[i][j] += aa[i] * bb[j];
        }
        __syncthreads();
    }
    #pragma unroll
    for (int i = 0; i < 4; ++i) {
        float4 o = make_float4(acc[i][0], acc[i][1], acc[i][2], acc[i][3]);
        *(float4*)(C + (size_t)(r0 + ty * 4 + i) * 256 + c0 + tx * 4) = o;
    }
}

__global__ __launch_bounds__(256) void row_stats(
    const float* __restrict__ X, float* __restrict__ mean,
    float* __restrict__ var)
{
    // one wave per row; rows of length 256; unbiased variance (ddof=1)
    const int row  = blockIdx.x * 4 + (threadIdx.x >> 6);
    const int lane = threadIdx.x & 63;
    float4 v = *(const float4*)(X + (size_t)row * 256 + lane * 4);
    float s  = v.x + v.y + v.z + v.w;
    float ss = v.x * v.x + v.y * v.y + v.z * v.z + v.w * v.w;
    #pragma unroll
    for (int off = 32; off > 0; off >>= 1) {
        s  += __shfl_down(s, off);
        ss += __shfl_down(ss, off);
    }
    if (lane == 0) {
        float m = s * (1.f / 256.f);
        mean[row] = m;
        var[row]  = (ss - 256.f * m * m) * (1.f / 255.f);
    }
}

__global__ __launch_bounds__(256) void fused_attn(
    const float* __restrict__ Q, const float* __restrict__ QF,
    const float* __restrict__ K, const float* __restrict__ V,
    const float* __restrict__ KF, const float* __restrict__ VF,
    const float* __restrict__ qm, const float* __restrict__ qv,
    const float* __restrict__ km, const float* __restrict__ kv,
    float* __restrict__ out)
{
    // BQ=16 queries per block, BK=64 keys per tile, D=256 in chunks of 64.
    // Scores are bounded (|s_c| <~ 0.5, |ssim| <~ 0.35): softmax without max-sub is safe.
    __shared__ float Qs[16][260];
    __shared__ float QFs[16][260];
    __shared__ float Ks[64][68];
    __shared__ float KFs[64][68];
    __shared__ float Pc[16][64];
    __shared__ float Ps[16][64];
    __shared__ float qms[16], qvs[16], kms[64], kvs[64], dcs[16], dss[16];

    const int tid = threadIdx.x;
    const int q0 = blockIdx.x * 16;

    // stage Q / QF tiles (16 x 256 each)
    #pragma unroll
    for (int it = 0; it < 4; ++it) {
        int i = tid + it * 256;        // float4 index in [0,1024)
        int r = i >> 6;
        int c = (i & 63) * 4;
        *(float4*)&Qs[r][c]  = *(const float4*)(Q  + (size_t)(q0 + r) * 256 + c);
        *(float4*)&QFs[r][c] = *(const float4*)(QF + (size_t)(q0 + r) * 256 + c);
    }
    if (tid < 16) { qms[tid] = qm[q0 + tid]; qvs[tid] = qv[q0 + tid]; }

    const int sqi = tid & 15;          // query row for score phase
    const int skb = (tid >> 4) * 4;    // key base (4 keys per thread)

    float acc_c[16] = {};
    float acc_s[16] = {};
    float denc = 0.f, dens = 0.f;      // meaningful for tid < 16

    for (int kt = 0; kt < 2048; kt += 64) {
        __syncthreads();  // P tiles from previous iter fully consumed
        if (tid < 64) { kms[tid] = km[kt + tid]; kvs[tid] = kv[kt + tid]; }
        float sc[4] = {};
        float sd[4] = {};
        for (int dc = 0; dc < 256; dc += 64) {
            #pragma unroll
            for (int it = 0; it < 4; ++it) {
                int i = tid + it * 256;   // float4 idx: 64 rows x 16 float4s
                int r = i >> 4;
                int c = (i & 15) * 4;
                *(float4*)&Ks[r][c]  = *(const float4*)(K  + (size_t)(kt + r) * 256 + dc + c);
                *(float4*)&KFs[r][c] = *(const float4*)(KF + (size_t)(kt + r) * 256 + dc + c);
            }
            __syncthreads();
            #pragma unroll
            for (int dd = 0; dd < 64; dd += 4) {
                float4 qa  = *(const float4*)&Qs[sqi][dc + dd];
                float4 qf4 = *(const float4*)&QFs[sqi][dc + dd];
                #pragma unroll
                for (int i = 0; i < 4; ++i) {
                    float4 kb  = *(const float4*)&Ks[skb + i][dd];
                    float4 kf4 = *(const float4*)&KFs[skb + i][dd];
                    sc[i] += qa.x * kb.x + qa.y * kb.y + qa.z * kb.z + qa.w * kb.w;
                    sd[i] += qf4.x * kf4.x + qf4.y * kf4.y + qf4.z * kf4.z + qf4.w * kf4.w;
                }
            }
            __syncthreads();
        }
        // epilogue: channel softmax numerator + SSIM score -> exp
        {
            float qmv = qms[sqi], qvv = qvs[sqi];
            #pragma unroll
            for (int i = 0; i < 4; ++i) {
                int kj = skb + i;
                float kmv = kms[kj], kvv = kvs[kj];
                float p1 = __expf(sc[i] * 0.0625f);
                float mp  = qmv * kmv;
                float cov = (sd[i] - 256.f * mp) * (1.f / 255.f);
                float num = (2.f * mp + 0.01f) * (2.f * cov + 0.03f);
                float den = (qmv * qmv + kmv * kmv + 0.01f) * (qvv + kvv + 0.03f);
                float ssim = num / (den + 1e-8f);
                float p2 = __expf(ssim);
                Pc[sqi][kj] = p1;
                Ps[sqi][kj] = p2;
            }
        }
        __syncthreads();
        // PV phase: thread owns output dim d = tid; coalesced V reads (read-once per block)
        const float* Vb  = V  + (size_t)kt * 256 + tid;
        const float* VFb = VF + (size_t)kt * 256 + tid;
        #pragma unroll 2
        for (int kj = 0; kj < 64; kj += 4) {
            float vc0 = Vb[(kj + 0) * 256], vc1 = Vb[(kj + 1) * 256];
            float vc2 = Vb[(kj + 2) * 256], vc3 = Vb[(kj + 3) * 256];
            float vs0 = VFb[(kj + 0) * 256], vs1 = VFb[(kj + 1) * 256];
            float vs2 = VFb[(kj + 2) * 256], vs3 = VFb[(kj + 3) * 256];
            #pragma unroll
            for (int qi = 0; qi < 16; ++qi) {
                float4 pc = *(const float4*)&Pc[qi][kj];
                float4 ps = *(const float4*)&Ps[qi][kj];
                acc_c[qi] += pc.x * vc0 + pc.y * vc1 + pc.z * vc2 + pc.w * vc3;
                acc_s[qi] += ps.x * vs0 + ps.y * vs1 + ps.z * vs2 + ps.w * vs3;
            }
        }
        if (tid < 16) {
            #pragma unroll
            for (int kj = 0; kj < 64; kj += 4) {
                float4 pc = *(const float4*)&Pc[tid][kj];
                float4 ps = *(const float4*)&Ps[tid][kj];
                denc += pc.x + pc.y + pc.z + pc.w;
                dens += ps.x + ps.y + ps.z + ps.w;
            }
        }
    }
    if (tid < 16) { dcs[tid] = denc; dss[tid] = dens; }
    __syncthreads();
    #pragma unroll
    for (int qi = 0; qi < 16; ++qi) {
        float rc = 1.f / dcs[qi];
        float rs = 1.f / dss[qi];
        out[(size_t)(q0 + qi) * 256 + tid] = acc_c[qi] * rc + acc_s[qi] * rs;
    }
}

extern "C" void kernel_launch(void* const* d_in, const int* in_sizes, int n_in,
                              void* d_out, int out_size, void* d_ws, size_t ws_size,
                              hipStream_t stream)
{
    const float* x      = (const float*)d_in[0];  // [12544, 256]
    const float* ch_mem = (const float*)d_in[1];  // [2048, 256]
    const float* ch_wq  = (const float*)d_in[2];
    const float* ch_wk  = (const float*)d_in[3];
    const float* ch_wv  = (const float*)d_in[4];
    const float* sp_mem = (const float*)d_in[5];  // [2048, 256] (16x16 flat)
    const float* sp_wq  = (const float*)d_in[6];
    const float* sp_wk  = (const float*)d_in[7];
    const float* sp_wv  = (const float*)d_in[8];
    float* out = (float*)d_out;
    float* ws  = (float*)d_ws;

    float* Q  = ws;                          // 12544*256
    float* QF = Q  + (size_t)12544 * 256;    // 12544*256
    float* K  = QF + (size_t)12544 * 256;    // 2048*256
    float* V  = K  + (size_t)2048 * 256;
    float* KF = V  + (size_t)2048 * 256;
    float* VF = KF + (size_t)2048 * 256;
    float* qm = VF + (size_t)2048 * 256;     // 12544
    float* qv = qm + 12544;
    float* km = qv + 12544;                  // 2048
    float* kv = km + 2048;
    // total ~34.2 MB of workspace

    dim3 blk(256);
    gemm_awt<<<dim3(196, 4), blk, 0, stream>>>(x, ch_wq, Q);
    gemm_awt<<<dim3(196, 4), blk, 0, stream>>>(x, sp_wq, QF);
    gemm_awt<<<dim3(32, 4),  blk, 0, stream>>>(ch_mem, ch_wk, K);
    gemm_awt<<<dim3(32, 4),  blk, 0, stream>>>(ch_mem, ch_wv, V);
    gemm_awt<<<dim3(32, 4),  blk, 0, stream>>>(sp_mem, sp_wk, KF);
    gemm_awt<<<dim3(32, 4),  blk, 0, stream>>>(sp_mem, sp_wv, VF);
    row_stats<<<dim3(12544 / 4), blk, 0, stream>>>(QF, qm, qv);
    row_stats<<<dim3(2048 / 4),  blk, 0, stream>>>(KF, km, kv);
    fused_attn<<<dim3(784), blk, 0, stream>>>(Q, QF, K, V, KF, VF, qm, qv, km, kv, out);
}

// Round 2
// 376.696 us; speedup vs baseline: 14.2133x; 14.2133x over previous
//
#include <hip/hip_runtime.h>

#define NBQ 12544
#define DM  256
#define MM  2048

typedef __attribute__((ext_vector_type(8))) __bf16 bf16x8;
typedef __attribute__((ext_vector_type(4))) float  floatx4;

__device__ __forceinline__ ushort f2bf(float x) {
    unsigned u = __float_as_uint(x);
    u += 0x7fffu + ((u >> 16) & 1u);   // RNE
    return (ushort)(u >> 16);
}
__device__ __forceinline__ float bf2f(ushort h) {
    return __uint_as_float(((unsigned)h) << 16);
}

// ---------------- projections: C = A * W^T, fp32 compute, bf16 store ----------------
// TRANS=0: C[r][c] row-major [nrows x 256]; TRANS=1: C^T[c][r]  [256 x nrows]
template <int TRANS>
__global__ __launch_bounds__(256) void gemm_proj(
    const float* __restrict__ A, const float* __restrict__ W,
    ushort* __restrict__ C, int nrows)
{
    __shared__ float As[16][68];
    __shared__ float Ws[16][68];
    const int tid = threadIdx.x;
    const int r0 = blockIdx.x * 64;
    const int c0 = blockIdx.y * 64;
    const int lr = tid >> 2;
    const int lk = (tid & 3) * 4;
    const int ty = tid >> 4;
    const int tx = tid & 15;
    float acc[4][4] = {};
    for (int d0 = 0; d0 < 256; d0 += 16) {
        float4 av = *(const float4*)(A + (size_t)(r0 + lr) * 256 + d0 + lk);
        float4 wv = *(const float4*)(W + (size_t)(c0 + lr) * 256 + d0 + lk);
        As[lk+0][lr] = av.x; As[lk+1][lr] = av.y; As[lk+2][lr] = av.z; As[lk+3][lr] = av.w;
        Ws[lk+0][lr] = wv.x; Ws[lk+1][lr] = wv.y; Ws[lk+2][lr] = wv.z; Ws[lk+3][lr] = wv.w;
        __syncthreads();
        #pragma unroll
        for (int kk = 0; kk < 16; ++kk) {
            float4 a = *(const float4*)&As[kk][ty * 4];
            float4 b = *(const float4*)&Ws[kk][tx * 4];
            float aa[4] = {a.x, a.y, a.z, a.w};
            float bb[4] = {b.x, b.y, b.z, b.w};
            #pragma unroll
            for (int i = 0; i < 4; ++i)
                #pragma unroll
                for (int j = 0; j < 4; ++j)
                    acc[i][j] += aa[i] * bb[j];
        }
        __syncthreads();
    }
    if (!TRANS) {
        #pragma unroll
        for (int i = 0; i < 4; ++i) {
            ushort4 o;
            o.x = f2bf(acc[i][0]); o.y = f2bf(acc[i][1]);
            o.z = f2bf(acc[i][2]); o.w = f2bf(acc[i][3]);
            *(ushort4*)(C + (size_t)(r0 + ty * 4 + i) * 256 + c0 + tx * 4) = o;
        }
    } else {
        #pragma unroll
        for (int j = 0; j < 4; ++j) {
            ushort4 o;
            o.x = f2bf(acc[0][j]); o.y = f2bf(acc[1][j]);
            o.z = f2bf(acc[2][j]); o.w = f2bf(acc[3][j]);
            *(ushort4*)(C + (size_t)(c0 + tx * 4 + j) * nrows + r0 + ty * 4) = o;
        }
    }
}

// ---------------- row stats from bf16 rows (mean, unbiased var) ----------------
__global__ __launch_bounds__(256) void row_stats_bf16(
    const ushort* __restrict__ X, float* __restrict__ mean, float* __restrict__ var)
{
    const int row  = blockIdx.x * 4 + (threadIdx.x >> 6);
    const int lane = threadIdx.x & 63;
    ushort4 u = *(const ushort4*)(X + (size_t)row * 256 + lane * 4);
    float a = bf2f(u.x), b = bf2f(u.y), c = bf2f(u.z), d = bf2f(u.w);
    float s  = a + b + c + d;
    float ss = a * a + b * b + c * c + d * d;
    #pragma unroll
    for (int off = 32; off > 0; off >>= 1) {
        s  += __shfl_down(s, off);
        ss += __shfl_down(ss, off);
    }
    if (lane == 0) {
        float m = s * (1.f / 256.f);
        mean[row] = m;
        var[row]  = (ss - 256.f * m * m) * (1.f / 255.f);
    }
}

// ---------------- fused dual attention, MFMA ----------------
// Block: 32 queries, 4 waves. Wave w: qhalf=w&1 (scores+PV rows), khalf/dhalf=w>>1.
// Key tiles of 32. Scores: A=Q regs, B=K LDS. PV: A=P LDS, B=Vt LDS.
__global__ __launch_bounds__(256, 2) void fused_attn_mfma(
    const ushort* __restrict__ Qb,  const ushort* __restrict__ QFb,
    const ushort* __restrict__ Kb,  const ushort* __restrict__ KFb,
    const ushort* __restrict__ Vtb, const ushort* __restrict__ VFtb,
    const float* __restrict__ qm_, const float* __restrict__ qv_,
    const float* __restrict__ km_, const float* __restrict__ kv_,
    float* __restrict__ out)
{
    __shared__ ushort K_lds[32][264];    // pad 264: row stride 528B -> 2-way banks, 16B aligned
    __shared__ ushort KF_lds[32][264];
    __shared__ ushort Vt_lds[256][40];   // [dim][key], pad 40: 80B stride -> 2-way, 16B aligned
    __shared__ ushort VFt_lds[256][40];
    __shared__ ushort P_lds[2][32][40];  // [branch][q][key]; aliased as den buffer at end
    // total LDS = 33792 + 40960 + 5120 = 79872 B -> 2 blocks/CU

    const int tid  = threadIdx.x;
    const int wv   = tid >> 6;
    const int lane = tid & 63;
    const int quad = lane >> 4;
    const int l16  = lane & 15;
    const int qsel = wv & 1;
    const int ksel = wv >> 1;     // also the dim-half for PV
    const int q0   = blockIdx.x * 32;

    // Q fragments in registers for the whole key loop (A layout: m=l16, k=quad*8+j)
    bf16x8 aQ[8], aQF[8];
    {
        const ushort* qp  = Qb  + (size_t)(q0 + qsel * 16 + l16) * DM + quad * 8;
        const ushort* qfp = QFb + (size_t)(q0 + qsel * 16 + l16) * DM + quad * 8;
        #pragma unroll
        for (int s = 0; s < 8; ++s) {
            aQ[s]  = *(const bf16x8*)(qp  + s * 32);
            aQF[s] = *(const bf16x8*)(qfp + s * 32);
        }
    }
    float qmv[4], qvv[4];
    #pragma unroll
    for (int r = 0; r < 4; ++r) {
        int qg = q0 + qsel * 16 + quad * 4 + r;
        qmv[r] = qm_[qg]; qvv[r] = qv_[qg];
    }

    floatx4 acc_c[8], acc_s[8];
    #pragma unroll
    for (int t = 0; t < 8; ++t) {
        acc_c[t] = (floatx4){0.f, 0.f, 0.f, 0.f};
        acc_s[t] = (floatx4){0.f, 0.f, 0.f, 0.f};
    }
    float denc_r[4] = {0.f, 0.f, 0.f, 0.f};
    float dens_r[4] = {0.f, 0.f, 0.f, 0.f};

    for (int kt = 0; kt < MM; kt += 32) {
        __syncthreads();  // previous tile's LDS fully consumed
        // stage K/KF tiles (coalesced 16B)
        #pragma unroll
        for (int it = 0; it < 4; ++it) {
            int idx = tid + it * 256;
            int r = idx >> 5, c8 = (idx & 31) * 8;
            *(uint4*)&K_lds[r][c8]  = *(const uint4*)(Kb  + (size_t)(kt + r) * DM + c8);
            *(uint4*)&KF_lds[r][c8] = *(const uint4*)(KFb + (size_t)(kt + r) * DM + c8);
        }
        // stage Vt/VFt tiles ([dim 256][key 32])
        #pragma unroll
        for (int it = 0; it < 4; ++it) {
            int idx = tid + it * 256;
            int d = idx >> 2, c8 = (idx & 3) * 8;
            *(uint4*)&Vt_lds[d][c8]  = *(const uint4*)(Vtb  + (size_t)d * MM + kt + c8);
            *(uint4*)&VFt_lds[d][c8] = *(const uint4*)(VFtb + (size_t)d * MM + kt + c8);
        }
        __syncthreads();

        // ---- scores: 16x16 tile (qhalf x khalf) per wave, both branches ----
        floatx4 sc = (floatx4){0.f, 0.f, 0.f, 0.f};
        floatx4 sd = (floatx4){0.f, 0.f, 0.f, 0.f};
        #pragma unroll
        for (int s = 0; s < 8; ++s) {
            bf16x8 bK  = *(const bf16x8*)&K_lds[ksel * 16 + l16][s * 32 + quad * 8];
            bf16x8 bKF = *(const bf16x8*)&KF_lds[ksel * 16 + l16][s * 32 + quad * 8];
            sc = __builtin_amdgcn_mfma_f32_16x16x32_bf16(aQ[s],  bK,  sc, 0, 0, 0);
            sd = __builtin_amdgcn_mfma_f32_16x16x32_bf16(aQF[s], bKF, sd, 0, 0, 0);
        }
        // ---- epilogue: exp(score/16) and SSIM -> P (bf16), den partials ----
        float kmv = km_[kt + ksel * 16 + l16];
        float kvv = kv_[kt + ksel * 16 + l16];
        #pragma unroll
        for (int r = 0; r < 4; ++r) {
            float p1  = __expf(sc[r] * 0.0625f);
            float mp  = qmv[r] * kmv;
            float cov = (sd[r] - 256.f * mp) * (1.f / 255.f);
            float num = (2.f * mp + 0.01f) * (2.f * cov + 0.03f);
            float den = (qmv[r] * qmv[r] + kmv * kmv + 0.01f) * (qvv[r] + kvv + 0.03f);
            float p2  = __expf(num / (den + 1e-8f));
            P_lds[0][qsel * 16 + quad * 4 + r][ksel * 16 + l16] = f2bf(p1);
            P_lds[1][qsel * 16 + quad * 4 + r][ksel * 16 + l16] = f2bf(p2);
            denc_r[r] += p1;
            dens_r[r] += p2;
        }
        __syncthreads();
        // ---- PV: A = P rows (qhalf), B = Vt (dhalf), K=32 keys in one step ----
        bf16x8 aPc = *(const bf16x8*)&P_lds[0][qsel * 16 + l16][quad * 8];
        bf16x8 aPs = *(const bf16x8*)&P_lds[1][qsel * 16 + l16][quad * 8];
        #pragma unroll
        for (int t = 0; t < 8; ++t) {
            int d0 = ksel * 128 + t * 16;
            bf16x8 bV  = *(const bf16x8*)&Vt_lds[d0 + l16][quad * 8];
            bf16x8 bVF = *(const bf16x8*)&VFt_lds[d0 + l16][quad * 8];
            acc_c[t] = __builtin_amdgcn_mfma_f32_16x16x32_bf16(aPc, bV,  acc_c[t], 0, 0, 0);
            acc_s[t] = __builtin_amdgcn_mfma_f32_16x16x32_bf16(aPs, bVF, acc_s[t], 0, 0, 0);
        }
    }

    // ---- denominators: reduce over the 16 key-lanes, combine key-halves via LDS ----
    #pragma unroll
    for (int r = 0; r < 4; ++r) {
        #pragma unroll
        for (int m = 1; m < 16; m <<= 1) {
            denc_r[r] += __shfl_xor(denc_r[r], m, 64);
            dens_r[r] += __shfl_xor(dens_r[r], m, 64);
        }
    }
    __syncthreads();  // all PV reads of P done; safe to alias
    float* denbuf = (float*)P_lds;  // [2 branches][2 khalf][32 q] = 128 floats
    if (l16 == 0) {
        #pragma unroll
        for (int r = 0; r < 4; ++r) {
            int q32 = qsel * 16 + quad * 4 + r;
            denbuf[ksel * 32 + q32]      = denc_r[r];
            denbuf[64 + ksel * 32 + q32] = dens_r[r];
        }
    }
    __syncthreads();
    #pragma unroll
    for (int r = 0; r < 4; ++r) {
        int q32 = qsel * 16 + quad * 4 + r;
        float rc = 1.f / (denbuf[q32] + denbuf[32 + q32]);
        float rs = 1.f / (denbuf[64 + q32] + denbuf[96 + q32]);
        float* orow = out + (size_t)(q0 + q32) * DM + ksel * 128 + l16;
        #pragma unroll
        for (int t = 0; t < 8; ++t)
            orow[t * 16] = acc_c[t][r] * rc + acc_s[t][r] * rs;
    }
}

extern "C" void kernel_launch(void* const* d_in, const int* in_sizes, int n_in,
                              void* d_out, int out_size, void* d_ws, size_t ws_size,
                              hipStream_t stream)
{
    const float* x      = (const float*)d_in[0];
    const float* ch_mem = (const float*)d_in[1];
    const float* ch_wq  = (const float*)d_in[2];
    const float* ch_wk  = (const float*)d_in[3];
    const float* ch_wv  = (const float*)d_in[4];
    const float* sp_mem = (const float*)d_in[5];
    const float* sp_wq  = (const float*)d_in[6];
    const float* sp_wk  = (const float*)d_in[7];
    const float* sp_wv  = (const float*)d_in[8];
    float* out = (float*)d_out;

    ushort* Qb   = (ushort*)d_ws;                 // [12544][256]
    ushort* QFb  = Qb   + (size_t)NBQ * DM;       // [12544][256]
    ushort* Kb   = QFb  + (size_t)NBQ * DM;       // [2048][256]
    ushort* KFb  = Kb   + (size_t)MM * DM;
    ushort* Vtb  = KFb  + (size_t)MM * DM;        // [256][2048] transposed
    ushort* VFtb = Vtb  + (size_t)MM * DM;
    float*  qm   = (float*)(VFtb + (size_t)MM * DM);
    float*  qv   = qm + NBQ;
    float*  km   = qv + NBQ;
    float*  kv   = km + MM;

    dim3 blk(256);
    gemm_proj<0><<<dim3(196, 4), blk, 0, stream>>>(x,      ch_wq, Qb,   NBQ);
    gemm_proj<0><<<dim3(196, 4), blk, 0, stream>>>(x,      sp_wq, QFb,  NBQ);
    gemm_proj<0><<<dim3(32, 4),  blk, 0, stream>>>(ch_mem, ch_wk, Kb,   MM);
    gemm_proj<0><<<dim3(32, 4),  blk, 0, stream>>>(sp_mem, sp_wk, KFb,  MM);
    gemm_proj<1><<<dim3(32, 4),  blk, 0, stream>>>(ch_mem, ch_wv, Vtb,  MM);
    gemm_proj<1><<<dim3(32, 4),  blk, 0, stream>>>(sp_mem, sp_wv, VFtb, MM);
    row_stats_bf16<<<dim3(NBQ / 4), blk, 0, stream>>>(QFb, qm, qv);
    row_stats_bf16<<<dim3(MM / 4),  blk, 0, stream>>>(KFb, km, kv);
    fused_attn_mfma<<<dim3(NBQ / 32), blk, 0, stream>>>(
        Qb, QFb, Kb, KFb, Vtb, VFtb, qm, qv, km, kv, out);
}